// Round 6
// baseline (1376.256 us; speedup 1.0000x reference)
//
#include <hip/hip_runtime.h>

#define N_NODES 100000
#define N_EDGES 1600000
#define D 128
#define TILE 64
#define NB 1563  // ceil(N_NODES/64) buckets of 64 rows
#define BIN_CHUNK 8192
#define BIN_BLOCKS ((N_EDGES + BIN_CHUNK - 1) / BIN_CHUNK)  // 196

typedef unsigned short u16;
typedef unsigned int u32;
typedef __attribute__((ext_vector_type(8))) short bf16x8;
typedef __attribute__((ext_vector_type(4))) float f32x4;

__device__ __forceinline__ u16 f2bf(float f) {
    u32 u = __float_as_uint(f);
    u += 0x7fffu + ((u >> 16) & 1u);  // round-to-nearest-even
    return (u16)(u >> 16);
}

// ---------------- conversions ----------------

// features fp32 [N,128] -> planar-packed bf16: featb[r*64+j] packs cols {j, j+64}
// (lane j of a gather wave needs exactly cols j and j+64 for the LDS-accum layout)
__global__ void convert_feat(const float* __restrict__ F, uint4* __restrict__ o4) {
    int gid = blockIdx.x * blockDim.x + threadIdx.x;  // [0, N*64/8) ; 8 u32 per thread
    int r = gid >> 3, j8 = (gid & 7) << 3;
    const float4* lo4 = (const float4*)&F[(size_t)r * 128 + j8];
    const float4* hi4 = (const float4*)&F[(size_t)r * 128 + 64 + j8];
    float4 a = lo4[0], b = lo4[1], c = hi4[0], d = hi4[1];
    float lo[8] = {a.x, a.y, a.z, a.w, b.x, b.y, b.z, b.w};
    float hi[8] = {c.x, c.y, c.z, c.w, d.x, d.y, d.z, d.w};
    u32 wv[8];
#pragma unroll
    for (int i = 0; i < 8; ++i) wv[i] = (u32)f2bf(lo[i]) | ((u32)f2bf(hi[i]) << 16);
    o4[gid * 2] = make_uint4(wv[0], wv[1], wv[2], wv[3]);
    o4[gid * 2 + 1] = make_uint4(wv[4], wv[5], wv[6], wv[7]);
}

// W[k][n] fp32 -> Wt[n][k] bf16, both 128x128
__global__ void convert_w(const float* __restrict__ W1, const float* __restrict__ W2,
                          u16* __restrict__ W1t, u16* __restrict__ W2t) {
    int flat = blockIdx.x * blockDim.x + threadIdx.x;  // [0, 32768)
    int m = flat >> 14;
    int idx = flat & 16383;
    int n = idx & 127;
    int k = idx >> 7;
    const float* src = m ? W2 : W1;
    u16* dst = m ? W2t : W1t;
    dst[n * 128 + k] = f2bf(src[k * 128 + n]);
}

// ---------------- bucket binning (no per-row sort needed anymore) ----------------

__global__ __launch_bounds__(256) void bucket_hist(const int* __restrict__ row,
                                                   int* __restrict__ bhist) {
    __shared__ int h[NB];
    int t = threadIdx.x;
    for (int i = t; i < NB; i += 256) h[i] = 0;
    __syncthreads();
    int base = blockIdx.x * BIN_CHUNK + t;
#pragma unroll
    for (int i = 0; i < 32; ++i) {
        int e = base + i * 256;
        if (e < N_EDGES) atomicAdd(&h[row[e] >> 6], 1);
    }
    __syncthreads();
    for (int i = t; i < NB; i += 256) {
        int c = h[i];
        if (c) atomicAdd(&bhist[i], c);
    }
}

__global__ void bucket_scan(const int* __restrict__ bhist, int* __restrict__ bucketOff,
                            int* __restrict__ bucketCursor) {
    __shared__ int part[256];
    int t = threadIdx.x;
    int v[8];
    int s = 0;
#pragma unroll
    for (int i = 0; i < 8; ++i) {
        int idx = t * 8 + i;
        v[i] = (idx < NB) ? bhist[idx] : 0;
        s += v[i];
    }
    int mine = s;
    part[t] = s;
    __syncthreads();
    for (int d = 1; d < 256; d <<= 1) {
        int x = (t >= d) ? part[t - d] : 0;
        __syncthreads();
        part[t] += x;
        __syncthreads();
    }
    int run = part[t] - mine;  // exclusive
#pragma unroll
    for (int i = 0; i < 8; ++i) {
        int idx = t * 8 + i;
        if (idx < NB) {
            bucketOff[idx] = run;
            bucketCursor[idx] = run;
        }
        run += v[i];
    }
    if (t == 0) bucketOff[NB] = N_EDGES;
}

// append edges grouped by bucket; pack row-local (6b) into col's high bits
__global__ __launch_bounds__(256) void bin_pass(const int* __restrict__ row,
                                                const int* __restrict__ col,
                                                const float* __restrict__ val,
                                                int* __restrict__ bucketCursor,
                                                int2* __restrict__ binned) {
    __shared__ int hist[NB];
    __shared__ int lbase[NB];
    int t = threadIdx.x;
    for (int i = t; i < NB; i += 256) hist[i] = 0;
    __syncthreads();
    int base = blockIdx.x * BIN_CHUNK;
    int r[32];
#pragma unroll
    for (int i = 0; i < 32; ++i) {
        int e = base + i * 256 + t;
        r[i] = (e < N_EDGES) ? row[e] : -1;
        if (r[i] >= 0) atomicAdd(&hist[r[i] >> 6], 1);
    }
    __syncthreads();
    for (int i = t; i < NB; i += 256) {
        int c = hist[i];
        lbase[i] = c ? atomicAdd(&bucketCursor[i], c) : 0;
    }
    __syncthreads();
    for (int i = t; i < NB; i += 256) hist[i] = 0;  // reuse as local cursor
    __syncthreads();
#pragma unroll
    for (int i = 0; i < 32; ++i) {
        if (r[i] < 0) continue;
        int e = base + i * 256 + t;
        int bkt = r[i] >> 6;
        int pos = lbase[bkt] + atomicAdd(&hist[bkt], 1);
        int2 ev;
        ev.x = col[e] | ((r[i] & 63) << 17);  // col < 2^17
        ev.y = __float_as_int(val[e]);
        binned[pos] = ev;
    }
}

// ---------------- mega: SpMM (LDS-atomic accum) + GEMM1 + GEMM2 ----------------
// Block = 64 rows. LDS: accF 64x128 f32 (32KB) overlaid later by Xt/H
// [64][136] bf16; Ws [128][72] bf16 K-half staging (bank pattern == proven
// 136-stride: (4*(n+q))%32, 8 words/bank, conflict-free).

__device__ __forceinline__ void stage_w_half(const u16* __restrict__ Wt, int kh,
                                             u16* __restrict__ Ws, int t) {
#pragma unroll
    for (int i = 0; i < 4; ++i) {
        int f = t + 256 * i;  // [0,1024) 16B chunks: 128 rows x 8
        int n = f >> 3;
        int c8 = (f & 7) << 3;
        *(uint4*)&Ws[n * 72 + c8] = *(const uint4*)&Wt[n * 128 + kh + c8];
    }
}

__device__ __forceinline__ void gemm_half(const u16* __restrict__ Xt,
                                          const u16* __restrict__ Ws, int arow, int khalf,
                                          int quad, int l16, f32x4 acc2[8]) {
#pragma unroll
    for (int kb = 0; kb < 64; kb += 32) {
        bf16x8 a = *(const bf16x8*)&Xt[arow * 136 + khalf + kb + quad * 8];
#pragma unroll
        for (int ct = 0; ct < 8; ++ct) {
            bf16x8 bb = *(const bf16x8*)&Ws[(ct * 16 + l16) * 72 + kb + quad * 8];
            acc2[ct] = __builtin_amdgcn_mfma_f32_16x16x32_bf16(a, bb, acc2[ct], 0, 0, 0);
        }
    }
}

__global__ __launch_bounds__(256, 3) void mega(
    const int2* __restrict__ binned, const int* __restrict__ bucketOff,
    const u32* __restrict__ featb, const u16* __restrict__ W1t,
    const u16* __restrict__ W2t, const float* __restrict__ b1,
    const float* __restrict__ b2, float* __restrict__ out) {
    __shared__ char smem[TILE * 128 * 4 + 128 * 72 * 2];  // 32768 + 18432 = 51200
    float* accF = (float*)smem;
    u16* Xt = (u16*)smem;  // overlay, used after accF is dead
    u16* Ws = (u16*)(smem + TILE * 128 * 4);

    int t = threadIdx.x;
    int w = t >> 6, lane = t & 63;
    int quad = lane >> 4, l16 = lane & 15;
    int row0 = blockIdx.x * TILE;

    // init accumulator with self-features (EPSILON=0: combined = F + neighbor)
#pragma unroll
    for (int i = 0; i < 16; ++i) {
        int idx = t + 256 * i;  // [0, 4096): 64 rows x 64 lanes
        int r = idx >> 6, l = idx & 63;
        int gr = row0 + r;
        if (gr > N_NODES - 1) gr = N_NODES - 1;  // dup rows beyond N; stores guarded
        u32 s = featb[gr * 64 + l];
        accF[r * 128 + l] = __uint_as_float(s << 16);
        accF[r * 128 + l + 64] = __uint_as_float(s & 0xffff0000u);
    }
    stage_w_half(W1t, 0, Ws, t);  // W1 k 0..63, survives the gather phase
    __syncthreads();

    // gather phase: wave-uniform scalar edge loads, 8 gathers in flight,
    // ds_add_f32 into the accumulator tile (2-way bank aliasing = free)
    int lo = bucketOff[blockIdx.x], hi = bucketOff[blockIdx.x + 1];
    int cnt = hi - lo;
    int wlo = __builtin_amdgcn_readfirstlane(lo + ((cnt * w) >> 2));
    int whi = __builtin_amdgcn_readfirstlane(lo + ((cnt * (w + 1)) >> 2));
    int j = wlo;
    for (; j + 8 <= whi; j += 8) {
        int2 e[8];
        u32 p[8];
#pragma unroll
        for (int u = 0; u < 8; ++u) e[u] = binned[j + u];
#pragma unroll
        for (int u = 0; u < 8; ++u) p[u] = featb[(e[u].x & 0x1FFFF) * 64 + lane];
#pragma unroll
        for (int u = 0; u < 8; ++u) {
            float v = __int_as_float(e[u].y);
            int rl = ((u32)e[u].x) >> 17;
            atomicAdd(&accF[rl * 128 + lane], v * __uint_as_float(p[u] << 16));
            atomicAdd(&accF[rl * 128 + lane + 64], v * __uint_as_float(p[u] & 0xffff0000u));
        }
    }
    for (; j < whi; ++j) {
        int2 e = binned[j];
        float v = __int_as_float(e.y);
        int rl = ((u32)e.x) >> 17;
        u32 p = featb[(e.x & 0x1FFFF) * 64 + lane];
        atomicAdd(&accF[rl * 128 + lane], v * __uint_as_float(p << 16));
        atomicAdd(&accF[rl * 128 + lane + 64], v * __uint_as_float(p & 0xffff0000u));
    }
    __syncthreads();

    // accF -> Xt bf16 (in-place overlay; regs + barrier make it safe).
    // thread t holds row t/4, cols (t&3)*32..+31 -> wave w converts exactly
    // its own GEMM rows 16w..16w+15.
    float tmp[32];
#pragma unroll
    for (int i = 0; i < 32; ++i) tmp[i] = accF[t * 32 + i];
    __syncthreads();
    {
        int r = t >> 2, c0 = (t & 3) << 5;
#pragma unroll
        for (int i = 0; i < 16; ++i) {
            u32 pk = (u32)f2bf(tmp[2 * i]) | ((u32)f2bf(tmp[2 * i + 1]) << 16);
            *(u32*)&Xt[r * 136 + c0 + 2 * i] = pk;
        }
    }
    __syncthreads();

    int arow = w * 16 + l16;

    // GEMM1 = relu(X @ W1 + b1), K in two staged halves
    f32x4 acc2[8];
#pragma unroll
    for (int ct = 0; ct < 8; ++ct) acc2[ct] = (f32x4){0.f, 0.f, 0.f, 0.f};
    gemm_half(Xt, Ws, arow, 0, quad, l16, acc2);
    __syncthreads();
    stage_w_half(W1t, 64, Ws, t);
    __syncthreads();
    gemm_half(Xt, Ws, arow, 64, quad, l16, acc2);

    // H (C-layout regs) -> bf16 into Xt region (wave-private rows, no barrier needed)
    float bv[8];
#pragma unroll
    for (int ct = 0; ct < 8; ++ct) bv[ct] = b1[ct * 16 + l16];
#pragma unroll
    for (int ct = 0; ct < 8; ++ct)
#pragma unroll
        for (int r = 0; r < 4; ++r) {
            float v = fmaxf(acc2[ct][r] + bv[ct], 0.f);
            Xt[(w * 16 + quad * 4 + r) * 136 + ct * 16 + l16] = f2bf(v);
        }
    __syncthreads();

    // GEMM2 = H @ W2 + b2
    stage_w_half(W2t, 0, Ws, t);
    __syncthreads();
#pragma unroll
    for (int ct = 0; ct < 8; ++ct) acc2[ct] = (f32x4){0.f, 0.f, 0.f, 0.f};
    gemm_half(Xt, Ws, arow, 0, quad, l16, acc2);
    __syncthreads();
    stage_w_half(W2t, 64, Ws, t);
    __syncthreads();
    gemm_half(Xt, Ws, arow, 64, quad, l16, acc2);

#pragma unroll
    for (int ct = 0; ct < 8; ++ct) bv[ct] = b2[ct * 16 + l16];
#pragma unroll
    for (int r = 0; r < 4; ++r) {
        int row = row0 + w * 16 + quad * 4 + r;
        if (row >= N_NODES) continue;
#pragma unroll
        for (int ct = 0; ct < 8; ++ct)
            out[(size_t)row * D + ct * 16 + l16] = acc2[ct][r] + bv[ct];
    }
}

extern "C" void kernel_launch(void* const* d_in, const int* in_sizes, int n_in,
                              void* d_out, int out_size, void* d_ws, size_t ws_size,
                              hipStream_t stream) {
    const int* indices = (const int*)d_in[0];      // [2, E]
    const float* values = (const float*)d_in[1];   // [E]
    const float* features = (const float*)d_in[2]; // [N, 128]
    const float* W1 = (const float*)d_in[3];
    const float* b1 = (const float*)d_in[4];
    const float* W2 = (const float*)d_in[5];
    const float* b2 = (const float*)d_in[6];
    float* out = (float*)d_out;

    const int* row = indices;
    const int* col = indices + N_EDGES;

    // ws: bhist[NB] | bucketOff[NB+1] | bucketCursor[NB] | pad | binned[E] int2 |
    //     featb[N*64] u32 | W1t[16384] u16 | W2t[16384] u16   (~38.5 MB)
    int* wsI = (int*)d_ws;
    int* bhist = wsI;                        // @0
    int* bucketOff = bhist + NB;             // @1563
    int* bucketCursor = bucketOff + NB + 1;  // @3127
    int2* binned = (int2*)(wsI + 4696);      // 16B-aligned
    u32* featb = (u32*)(binned + N_EDGES);
    u16* W1t = (u16*)(featb + (size_t)N_NODES * 64);
    u16* W2t = W1t + 16384;

    hipMemsetAsync(bhist, 0, NB * sizeof(int), stream);

    convert_feat<<<N_NODES * 64 / 8 / 256, 256, 0, stream>>>(features, (uint4*)featb);
    convert_w<<<128, 256, 0, stream>>>(W1, W2, W1t, W2t);
    bucket_hist<<<BIN_BLOCKS, 256, 0, stream>>>(row, bhist);
    bucket_scan<<<1, 256, 0, stream>>>(bhist, bucketOff, bucketCursor);
    bin_pass<<<BIN_BLOCKS, 256, 0, stream>>>(row, col, values, bucketCursor, binned);
    mega<<<NB, 256, 0, stream>>>(binned, bucketOff, featb, W1t, W2t, b1, b2, out);
}

// Round 7
// 289.399 us; speedup vs baseline: 4.7556x; 4.7556x over previous
//
#include <hip/hip_runtime.h>

#define N_NODES 100000
#define N_EDGES 1600000
#define D 128
#define NB 782    // buckets of 128 rows
#define BCAP 2560 // per-bucket capacity: mean 2046, sigma 45 -> +11 sigma

typedef unsigned short u16;
typedef unsigned int u32;
typedef __attribute__((ext_vector_type(8))) short bf16x8;
typedef __attribute__((ext_vector_type(4))) float f32x4;

__device__ __forceinline__ u16 f2bf(float f) {
    u32 u = __float_as_uint(f);
    u += 0x7fffu + ((u >> 16) & 1u);  // round-to-nearest-even
    return (u16)(u >> 16);
}

// ---------------- bf16 conversions ----------------

// features fp32 [N,128] -> bf16 packed (word j = cols {2j,2j+1})
__global__ void convert_feat(const float4* __restrict__ f4, uint4* __restrict__ o4) {
    int idx = blockIdx.x * blockDim.x + threadIdx.x;  // [0, N*D/8)
    float4 a = f4[idx * 2], b = f4[idx * 2 + 1];
    uint4 o;
    o.x = (u32)f2bf(a.x) | ((u32)f2bf(a.y) << 16);
    o.y = (u32)f2bf(a.z) | ((u32)f2bf(a.w) << 16);
    o.z = (u32)f2bf(b.x) | ((u32)f2bf(b.y) << 16);
    o.w = (u32)f2bf(b.z) | ((u32)f2bf(b.w) << 16);
    o4[idx] = o;
}

// W[k][n] fp32 -> Wt[n][k] bf16, both 128x128
__global__ void convert_w(const float* __restrict__ W1, const float* __restrict__ W2,
                          u16* __restrict__ W1t, u16* __restrict__ W2t) {
    int flat = blockIdx.x * blockDim.x + threadIdx.x;  // [0, 32768)
    int m = flat >> 14;
    int idx = flat & 16383;
    int n = idx & 127;
    int k = idx >> 7;
    const float* src = m ? W2 : W1;
    u16* dst = m ? W2t : W1t;
    dst[n * 128 + k] = f2bf(src[k * 128 + n]);
}

// ---------------- bucketed CSR build (capacity bins, no global scan) ----------------

// append edges into fixed-capacity buckets; pack row-local (7b) into col's high bits
__global__ __launch_bounds__(256) void bin_pass(const int* __restrict__ row,
                                                const int* __restrict__ col,
                                                const float* __restrict__ val,
                                                int* __restrict__ bucketCount,
                                                int2* __restrict__ binned) {
    __shared__ int hist[NB];
    __shared__ int lbase[NB];
    int t = threadIdx.x;
    for (int i = t; i < NB; i += 256) hist[i] = 0;
    __syncthreads();
    int base = blockIdx.x * 4096;
    int r[16];
#pragma unroll
    for (int i = 0; i < 16; ++i) {
        int e = base + i * 256 + t;
        r[i] = (e < N_EDGES) ? row[e] : -1;
        if (r[i] >= 0) atomicAdd(&hist[r[i] >> 7], 1);
    }
    __syncthreads();
    for (int i = t; i < NB; i += 256) {
        int c = hist[i];
        lbase[i] = c ? atomicAdd(&bucketCount[i], c) : 0;
    }
    __syncthreads();
    for (int i = t; i < NB; i += 256) hist[i] = 0;  // reuse as local cursor
    __syncthreads();
#pragma unroll
    for (int i = 0; i < 16; ++i) {
        if (r[i] < 0) continue;
        int e = base + i * 256 + t;
        int bkt = r[i] >> 7;
        int pos = bkt * BCAP + lbase[bkt] + atomicAdd(&hist[bkt], 1);
        int2 ev;
        ev.x = col[e] | ((r[i] & 127) << 17);  // col < 2^17
        ev.y = __float_as_int(val[e]);
        binned[pos] = ev;
    }
}

// one block per bucket: per-row counts -> rowRange (beg,end), scatter into
// row-sorted scev. All writes land in the bucket's own ~20KB window.
__global__ __launch_bounds__(256) void bucket_sort(const int2* __restrict__ binned,
                                                   const int* __restrict__ bucketCount,
                                                   int2* __restrict__ rowRange,
                                                   int2* __restrict__ scev) {
    __shared__ int h[128];
    __shared__ int cur[128];
    int b = blockIdx.x, t = threadIdx.x;
    int row0 = b << 7;
    int nrows = N_NODES - row0;
    if (nrows > 128) nrows = 128;
    if (t < 128) h[t] = 0;
    __syncthreads();
    int lo = b * BCAP;
    int hi = lo + bucketCount[b];
    for (int i = lo + t; i < hi; i += 256)
        atomicAdd(&h[((u32)binned[i].x) >> 17], 1);
    __syncthreads();
    if (t < 128) cur[t] = h[t];
    __syncthreads();
    for (int d = 1; d < 128; d <<= 1) {
        int x = 0;
        if (t < 128 && t >= d) x = cur[t - d];
        __syncthreads();
        if (t < 128) cur[t] += x;
        __syncthreads();
    }
    if (t < 128) {
        int excl = lo + cur[t] - h[t];
        if (t < nrows) rowRange[row0 + t] = make_int2(excl, excl + h[t]);
        cur[t] = excl;  // per-row cursor
    }
    __syncthreads();
    for (int i = lo + t; i < hi; i += 256) {
        int2 ev = binned[i];
        int rl = ((u32)ev.x) >> 17;
        int pos = atomicAdd(&cur[rl], 1);
        scev[pos] = make_int2(ev.x & 0x1FFFF, ev.y);
    }
}

// ---------------- SpMM (bf16 gather): one wave per row ----------------
// Xb[r] = bf16( featb[r] + sum_j v_j * featb[col_j] )
// wid wave-uniform via readfirstlane -> rowRange/scev become scalar loads;
// 16-deep batches keep 16 independent 256B gathers in flight per wave.

__global__ __launch_bounds__(256) void spmm_bf16(
    const int2* __restrict__ scev, const int2* __restrict__ rowRange,
    const u32* __restrict__ featb, u32* __restrict__ Xb) {
    int wid0 = (blockIdx.x * blockDim.x + threadIdx.x) >> 6;
    int wid = __builtin_amdgcn_readfirstlane(wid0);
    int lane = threadIdx.x & 63;
    if (wid >= N_NODES) return;
    int2 rr = rowRange[wid];
    int j = rr.x, end = rr.y;
    u32 self = featb[wid * 64 + lane];
    float ax0 = __uint_as_float(self << 16);
    float ay0 = __uint_as_float(self & 0xffff0000u);
    float ax1 = 0.f, ay1 = 0.f;
    for (; j + 16 <= end; j += 16) {
        int2 e[16];
        u32 p[16];
#pragma unroll
        for (int u = 0; u < 16; ++u) e[u] = scev[j + u];
#pragma unroll
        for (int u = 0; u < 16; ++u) p[u] = featb[e[u].x * 64 + lane];
#pragma unroll
        for (int u = 0; u < 16; ++u) {
            float v = __int_as_float(e[u].y);
            float lo = __uint_as_float(p[u] << 16);
            float hi = __uint_as_float(p[u] & 0xffff0000u);
            if (u & 1) {
                ax1 += v * lo;
                ay1 += v * hi;
            } else {
                ax0 += v * lo;
                ay0 += v * hi;
            }
        }
    }
    for (; j + 4 <= end; j += 4) {
        int2 e[4];
        u32 p[4];
#pragma unroll
        for (int u = 0; u < 4; ++u) e[u] = scev[j + u];
#pragma unroll
        for (int u = 0; u < 4; ++u) p[u] = featb[e[u].x * 64 + lane];
#pragma unroll
        for (int u = 0; u < 4; ++u) {
            float v = __int_as_float(e[u].y);
            float lo = __uint_as_float(p[u] << 16);
            float hi = __uint_as_float(p[u] & 0xffff0000u);
            if (u & 1) {
                ax1 += v * lo;
                ay1 += v * hi;
            } else {
                ax0 += v * lo;
                ay0 += v * hi;
            }
        }
    }
    for (; j < end; ++j) {
        int2 e = scev[j];
        float v = __int_as_float(e.y);
        u32 p = featb[e.x * 64 + lane];
        ax0 += v * __uint_as_float(p << 16);
        ay0 += v * __uint_as_float(p & 0xffff0000u);
    }
    float accx = ax0 + ax1;
    float accy = ay0 + ay1;
    Xb[wid * 64 + lane] = (u32)f2bf(accx) | ((u32)f2bf(accy) << 16);
}

// ---------------- MFMA bf16 GEMM: out = act(X @ W + b) ---------------- (R5-proven)

template <int RELU, int OUT32>
__global__ __launch_bounds__(256, 2) void gemm_mfma(
    const u16* __restrict__ Xb, const u16* __restrict__ Wt,
    const float* __restrict__ bias, u16* __restrict__ outb, float* __restrict__ outf) {
    __shared__ u16 Ws[128][136];
    int t = threadIdx.x;
    {
        const uint4* wsrc = (const uint4*)Wt;
#pragma unroll
        for (int i = 0; i < 8; ++i) {
            int f = t + 256 * i;
            int n = f >> 4;
            int c8 = (f & 15) << 3;
            *(uint4*)&Ws[n][c8] = wsrc[f];
        }
    }
    __syncthreads();

    int w = t >> 6, lane = t & 63;
    int quad = lane >> 4, l16 = lane & 15;
    int row0 = blockIdx.x * 128 + w * 32;

    f32x4 acc[2][8];
#pragma unroll
    for (int rt = 0; rt < 2; ++rt)
#pragma unroll
        for (int ct = 0; ct < 8; ++ct) acc[rt][ct] = (f32x4){0.f, 0.f, 0.f, 0.f};

    int ra = row0 + l16;
    int rb = row0 + 16 + l16;
    if (ra > N_NODES - 1) ra = N_NODES - 1;
    if (rb > N_NODES - 1) rb = N_NODES - 1;
    const u16* pa = Xb + (size_t)ra * D + quad * 8;
    const u16* pb = Xb + (size_t)rb * D + quad * 8;

#pragma unroll
    for (int kb = 0; kb < 128; kb += 32) {
        bf16x8 a0 = *(const bf16x8*)(pa + kb);
        bf16x8 a1 = *(const bf16x8*)(pb + kb);
#pragma unroll
        for (int ct = 0; ct < 8; ++ct) {
            bf16x8 b = *(const bf16x8*)&Ws[ct * 16 + l16][kb + quad * 8];
            acc[0][ct] = __builtin_amdgcn_mfma_f32_16x16x32_bf16(a0, b, acc[0][ct], 0, 0, 0);
            acc[1][ct] = __builtin_amdgcn_mfma_f32_16x16x32_bf16(a1, b, acc[1][ct], 0, 0, 0);
        }
    }

    float bv[8];
#pragma unroll
    for (int ct = 0; ct < 8; ++ct) bv[ct] = bias[ct * 16 + l16];

#pragma unroll
    for (int rt = 0; rt < 2; ++rt) {
#pragma unroll
        for (int r = 0; r < 4; ++r) {
            int row = row0 + rt * 16 + quad * 4 + r;
            if (row >= N_NODES) continue;
#pragma unroll
            for (int ct = 0; ct < 8; ++ct) {
                float v = acc[rt][ct][r] + bv[ct];
                if (RELU) v = fmaxf(v, 0.f);
                int col = ct * 16 + l16;
                if (OUT32) outf[(size_t)row * D + col] = v;
                else outb[(size_t)row * D + col] = f2bf(v);
            }
        }
    }
}

extern "C" void kernel_launch(void* const* d_in, const int* in_sizes, int n_in,
                              void* d_out, int out_size, void* d_ws, size_t ws_size,
                              hipStream_t stream) {
    const int* indices = (const int*)d_in[0];      // [2, E]
    const float* values = (const float*)d_in[1];   // [E]
    const float* features = (const float*)d_in[2]; // [N, 128]
    const float* W1 = (const float*)d_in[3];
    const float* b1 = (const float*)d_in[4];
    const float* W2 = (const float*)d_in[5];
    const float* b2 = (const float*)d_in[6];

    const int* row = indices;
    const int* col = indices + N_EDGES;

    // ws (ints): bucketCount[NB] pad | rowRange[N] int2 | scev[NB*BCAP] int2 |
    //            featb[N*64] u32 | W1t/W2t u16      total ~42.5 MB
    int* wsI = (int*)d_ws;
    int* bucketCount = wsI;                            // @0, NB ints
    int2* rowRange = (int2*)(wsI + 784);               // 800 KB
    int2* scev = (int2*)(wsI + 784 + 2 * N_NODES);     // 16.0 MB
    u32* featb = (u32*)(wsI + 784 + 2 * N_NODES + 2 * NB * BCAP);  // 25.6 MB, 16B-aligned
    u16* Hb = (u16*)featb;  // reuse: featb dead after spmm
    u16* W1t = (u16*)(featb + (size_t)N_NODES * 64);
    u16* W2t = W1t + 16384;

    // d_out: binned[NB*BCAP] int2 (16.0 MB, dead after bucket_sort) in lower part;
    // Xb (combined bf16, 25.6 MB) in upper half; gemm2 overwrites everything.
    int2* binned = (int2*)d_out;
    u32* Xb = (u32*)((char*)d_out + (size_t)N_NODES * D * 2);
    float* outf = (float*)d_out;

    hipMemsetAsync(bucketCount, 0, NB * sizeof(int), stream);

    convert_feat<<<N_NODES * D / 8 / 256, 256, 0, stream>>>((const float4*)features, (uint4*)featb);
    convert_w<<<128, 256, 0, stream>>>(W1, W2, W1t, W2t);

    int cb = (N_EDGES + 4095) / 4096;  // 391
    bin_pass<<<cb, 256, 0, stream>>>(row, col, values, bucketCount, binned);
    bucket_sort<<<NB, 256, 0, stream>>>(binned, bucketCount, rowRange, scev);

    spmm_bf16<<<(N_NODES * 64 + 255) / 256, 256, 0, stream>>>(scev, rowRange, featb, Xb);

    int gb = (N_NODES + 127) / 128;  // 782
    gemm_mfma<1, 0><<<gb, 256, 0, stream>>>((const u16*)Xb, W1t, b1, Hb, nullptr);
    gemm_mfma<0, 1><<<gb, 256, 0, stream>>>(Hb, W2t, b2, nullptr, outf);
}